// Round 1
// baseline (919.107 us; speedup 1.0000x reference)
//
#include <hip/hip_runtime.h>

#define MPTS 1048576

// ---------------- workspace layout ----------------
static const size_t OFF_Z      = 0;            // float z = MLP(0)
static const size_t OFF_CNT    = 64;           // int active count
static const size_t OFF_PL     = 256;          // 3 planes HWC: 3*65536 floats
static const size_t OFF_W2T    = OFF_PL + 3ull*65536*4;     // 16384 floats
static const size_t OFF_LIST   = OFF_W2T + 16384ull*4;      // M ints
static const size_t WS_NEED    = OFF_LIST + (size_t)MPTS*4; // ~4.8 MB

__device__ __forceinline__ int iclamp(int v, int lo, int hi) {
    return v < lo ? lo : (v > hi ? hi : v);
}

// Bilinear sample of one 64-channel plane at (pa, pb) in pixel coords.
// HWC=true: plane laid out [32][32][64] (y,x,c). HWC=false: original [64][32][32].
// Accumulates into f[64] (set if mult==false, multiply if true).
template<bool HWC>
__device__ __forceinline__ void sample_plane(const float* __restrict__ plane,
                                             float pa, float pb,
                                             float* __restrict__ f, const bool mult) {
    float fa = floorf(pa), fb = floorf(pb);
    int ia0 = (int)fa, ib0 = (int)fb;
    int ia1 = ia0 + 1, ib1 = ib0 + 1;
    float wa1 = pa - fa, wa0 = 1.0f - wa1;
    float wb1 = pb - fb, wb0 = 1.0f - wb1;
    // zero the 1-D weight when its index is out of bounds (zero-padding semantics)
    float va0 = (ia0 >= 0 && ia0 < 32) ? wa0 : 0.0f;
    float va1 = (ia1 >= 0 && ia1 < 32) ? wa1 : 0.0f;
    float vb0 = (ib0 >= 0 && ib0 < 32) ? wb0 : 0.0f;
    float vb1 = (ib1 >= 0 && ib1 < 32) ? wb1 : 0.0f;
    int ca0 = iclamp(ia0, 0, 31), ca1 = iclamp(ia1, 0, 31);
    int cb0 = iclamp(ib0, 0, 31), cb1 = iclamp(ib1, 0, 31);
    float w00 = va0 * vb0, w01 = va1 * vb0, w10 = va0 * vb1, w11 = va1 * vb1;
    if (HWC) {
        const float4* p00 = (const float4*)(plane + (cb0 * 32 + ca0) * 64);
        const float4* p01 = (const float4*)(plane + (cb0 * 32 + ca1) * 64);
        const float4* p10 = (const float4*)(plane + (cb1 * 32 + ca0) * 64);
        const float4* p11 = (const float4*)(plane + (cb1 * 32 + ca1) * 64);
#pragma unroll
        for (int q = 0; q < 16; ++q) {
            float4 g00 = p00[q], g01 = p01[q], g10 = p10[q], g11 = p11[q];
            float vx = fmaf(w00, g00.x, fmaf(w01, g01.x, fmaf(w10, g10.x, w11 * g11.x)));
            float vy = fmaf(w00, g00.y, fmaf(w01, g01.y, fmaf(w10, g10.y, w11 * g11.y)));
            float vz = fmaf(w00, g00.z, fmaf(w01, g01.z, fmaf(w10, g10.z, w11 * g11.z)));
            float vw = fmaf(w00, g00.w, fmaf(w01, g01.w, fmaf(w10, g10.w, w11 * g11.w)));
            if (mult) {
                f[4*q+0] *= vx; f[4*q+1] *= vy; f[4*q+2] *= vz; f[4*q+3] *= vw;
            } else {
                f[4*q+0] = vx; f[4*q+1] = vy; f[4*q+2] = vz; f[4*q+3] = vw;
            }
        }
    } else {
        int o00 = cb0 * 32 + ca0, o01 = cb0 * 32 + ca1;
        int o10 = cb1 * 32 + ca0, o11 = cb1 * 32 + ca1;
#pragma unroll
        for (int c = 0; c < 64; ++c) {
            const float* pc = plane + c * 1024;
            float v = fmaf(w00, pc[o00], fmaf(w01, pc[o01],
                      fmaf(w10, pc[o10], w11 * pc[o11])));
            if (mult) f[c] *= v; else f[c] = v;
        }
    }
}

// K0: z = MLP(zero features); also zero the compaction counter. 1 block x 128.
__global__ void k_init_z(const float* __restrict__ w2, const float* __restrict__ b1,
                         const float* __restrict__ b2, const float* __restrict__ w3,
                         const float* __restrict__ b3, float* __restrict__ zout,
                         int* __restrict__ cnt) {
    int p = threadIdx.x;  // 128 threads
    if (p == 0) *cnt = 0;
    float h2p = b2[p];
    for (int o = 0; o < 128; ++o) h2p += w2[p * 128 + o] * fmaxf(b1[o], 0.0f);
    __shared__ float red[128];
    red[p] = fmaxf(h2p, 0.0f) * w3[p];
    __syncthreads();
    for (int s = 64; s > 0; s >>= 1) {
        if (p < s) red[p] += red[p + s];
        __syncthreads();
    }
    if (p == 0) *zout = red[0] + b3[0];
}

// K1: transpose planes CHW->HWC and w2 [p][o] -> w2t [o][p]. 832 blocks x 256.
__global__ void k_prep(const float* __restrict__ pxy, const float* __restrict__ pyz,
                       const float* __restrict__ pxz, const float* __restrict__ w2,
                       float* __restrict__ planes, float* __restrict__ w2t) {
    int tid = blockIdx.x * 256 + threadIdx.x;
    if (tid < 3 * 65536) {
        int t = tid >> 16;
        int r = tid & 65535;
        int hw = r >> 6;
        int c = r & 63;
        const float* src = (t == 0) ? pxy : ((t == 1) ? pyz : pxz);
        planes[tid] = src[c * 1024 + hw];
    } else {
        int r = tid - 3 * 65536;
        if (r < 16384) {
            int o = r >> 7, p = r & 127;
            w2t[o * 128 + p] = w2[p * 128 + o];
        }
    }
}

// K2: classify points; inactive -> out = z; active -> append index to list. 4096 x 256.
__global__ void k_classify(const float* __restrict__ coords, const float* __restrict__ zptr,
                           int* __restrict__ cnt, int* __restrict__ list,
                           float* __restrict__ out) {
    int i = blockIdx.x * 256 + threadIdx.x;
    if (i >= MPTS) return;
    float x = coords[3 * i + 0], y = coords[3 * i + 1], z = coords[3 * i + 2];
    float px = fmaf(x, 15.5f, 15.5f);
    float py = fmaf(y, 15.5f, 15.5f);
    float pz = fmaf(z, 15.5f, 15.5f);
    bool act = (px > -1.0f) & (px < 32.0f) & (py > -1.0f) & (py < 32.0f) &
               (pz > -1.0f) & (pz < 32.0f);
    unsigned long long m = __ballot(act);
    int lane = threadIdx.x & 63;
    if (m) {
        int ldr = __ffsll((long long)m) - 1;
        int base = 0;
        if (lane == ldr) base = atomicAdd(cnt, __popcll(m));
        base = __shfl(base, ldr, 64);
        if (act) list[base + __popcll(m & ((1ull << lane) - 1ull))] = i;
    }
    if (!act) out[i] = *zptr;
}

// K3: full pipeline per point.
// FULL=true: compacted list + HWC planes + transposed w2 (w2 arg = w2t [o][p]).
// FULL=false: all M points, original layouts (fallback; zero features -> z naturally).
template<bool FULL>
__global__ __launch_bounds__(256, 2)
void k_main(const float* __restrict__ coords,
            const float* __restrict__ pl0, const float* __restrict__ pl1,
            const float* __restrict__ pl2,
            const float* __restrict__ w1, const float* __restrict__ b1,
            const float* __restrict__ w2, const float* __restrict__ b2,
            const float* __restrict__ w3, const float* __restrict__ b3,
            const int* __restrict__ cnt, const int* __restrict__ list,
            float* __restrict__ out) {
    int gsz = gridDim.x * blockDim.x;
    int start = blockIdx.x * blockDim.x + threadIdx.x;
    int n = FULL ? *cnt : MPTS;
    for (int idx = start; idx < n; idx += gsz) {
        int i = FULL ? list[idx] : idx;
        float x = coords[3 * i + 0], y = coords[3 * i + 1], z = coords[3 * i + 2];
        float px = fmaf(x, 15.5f, 15.5f);
        float py = fmaf(y, 15.5f, 15.5f);
        float pz = fmaf(z, 15.5f, 15.5f);

        float feat[64];
        sample_plane<FULL>(pl0, px, py, feat, false);  // xy plane: (x, y)
        sample_plane<FULL>(pl1, py, pz, feat, true);   // yz plane: (y, z)
        sample_plane<FULL>(pl2, px, pz, feat, true);   // xz plane: (x, z)

        float h2[128];
#pragma unroll
        for (int p = 0; p < 128; ++p) h2[p] = b2[p];

#pragma unroll 2
        for (int o = 0; o < 128; ++o) {
            float acc = b1[o];
            const float* w1r = w1 + o * 64;
#pragma unroll
            for (int c = 0; c < 64; ++c) acc = fmaf(feat[c], w1r[c], acc);
            float r = fmaxf(acc, 0.0f);
            if (FULL) {
                const float* w2r = w2 + o * 128;  // w2t row o, contiguous
#pragma unroll
                for (int p = 0; p < 128; ++p) h2[p] = fmaf(r, w2r[p], h2[p]);
            } else {
#pragma unroll
                for (int p = 0; p < 128; ++p) h2[p] = fmaf(r, w2[p * 128 + o], h2[p]);
            }
        }
        float oa = b3[0];
#pragma unroll
        for (int p = 0; p < 128; ++p) oa = fmaf(fmaxf(h2[p], 0.0f), w3[p], oa);
        out[i] = oa;
    }
}

extern "C" void kernel_launch(void* const* d_in, const int* in_sizes, int n_in,
                              void* d_out, int out_size, void* d_ws, size_t ws_size,
                              hipStream_t stream) {
    const float* coords = (const float*)d_in[0];
    const float* pxy    = (const float*)d_in[1];
    const float* pyz    = (const float*)d_in[2];
    const float* pxz    = (const float*)d_in[3];
    const float* w1     = (const float*)d_in[4];
    const float* b1     = (const float*)d_in[5];
    const float* w2     = (const float*)d_in[6];
    const float* b2     = (const float*)d_in[7];
    const float* w3     = (const float*)d_in[8];
    const float* b3     = (const float*)d_in[9];
    float* out = (float*)d_out;

    if (ws_size >= WS_NEED) {
        float* zout   = (float*)((char*)d_ws + OFF_Z);
        int*   cnt    = (int*)((char*)d_ws + OFF_CNT);
        float* planes = (float*)((char*)d_ws + OFF_PL);
        float* w2t    = (float*)((char*)d_ws + OFF_W2T);
        int*   list   = (int*)((char*)d_ws + OFF_LIST);

        k_init_z<<<1, 128, 0, stream>>>(w2, b1, b2, w3, b3, zout, cnt);
        k_prep<<<832, 256, 0, stream>>>(pxy, pyz, pxz, w2, planes, w2t);
        k_classify<<<4096, 256, 0, stream>>>(coords, zout, cnt, list, out);
        k_main<true><<<2048, 256, 0, stream>>>(coords,
                                               planes, planes + 65536, planes + 131072,
                                               w1, b1, w2t, b2, w3, b3,
                                               cnt, list, out);
    } else {
        // Fallback: no workspace needed; compute every point (zero features give z).
        k_main<false><<<4096, 256, 0, stream>>>(coords, pxy, pyz, pxz,
                                                w1, b1, w2, b2, w3, b3,
                                                nullptr, nullptr, out);
    }
}

// Round 2
// 307.801 us; speedup vs baseline: 2.9860x; 2.9860x over previous
//
#include <hip/hip_runtime.h>

#define MPTS 1048576

typedef _Float16 f16;
typedef _Float16 f16x8 __attribute__((ext_vector_type(8)));
typedef float f32x4 __attribute__((ext_vector_type(4)));

// ---------------- workspace layout (bytes) ----------------
static const size_t OFF_Z    = 0;                         // float
static const size_t OFF_CNT  = 64;                        // int
static const size_t OFF_PL   = 256;                       // 3 planes HWC f32: 786432 B
static const size_t OFF_W1H  = OFF_PL + 786432;           // 8192 f16 = 16 KB
static const size_t OFF_W2H  = OFF_W1H + 16384;           // 16384 f16 = 32 KB
static const size_t OFF_LIST = OFF_W2H + 32768;           // M ints
static const size_t WS_NEED  = OFF_LIST + (size_t)MPTS * 4;

__device__ __forceinline__ int iclamp(int v, int lo, int hi) {
    return v < lo ? lo : (v > hi ? hi : v);
}

// -------- bilinear sample of 16 channels (HWC plane [32][32][64] f32) --------
__device__ __forceinline__ void samp16(const float* __restrict__ pl,
                                       float pa, float pb, int c0,
                                       float* __restrict__ f, const bool mult) {
    float fa = floorf(pa), fb = floorf(pb);
    int ia0 = (int)fa, ib0 = (int)fb;
    int ia1 = ia0 + 1, ib1 = ib0 + 1;
    float wa1 = pa - fa, wa0 = 1.0f - wa1;
    float wb1 = pb - fb, wb0 = 1.0f - wb1;
    float va0 = (ia0 >= 0 && ia0 < 32) ? wa0 : 0.0f;
    float va1 = (ia1 >= 0 && ia1 < 32) ? wa1 : 0.0f;
    float vb0 = (ib0 >= 0 && ib0 < 32) ? wb0 : 0.0f;
    float vb1 = (ib1 >= 0 && ib1 < 32) ? wb1 : 0.0f;
    int ca0 = iclamp(ia0, 0, 31), ca1 = iclamp(ia1, 0, 31);
    int cb0 = iclamp(ib0, 0, 31), cb1 = iclamp(ib1, 0, 31);
    float w00 = va0 * vb0, w01 = va1 * vb0, w10 = va0 * vb1, w11 = va1 * vb1;
    const float4* p00 = (const float4*)(pl + (cb0 * 32 + ca0) * 64 + c0);
    const float4* p01 = (const float4*)(pl + (cb0 * 32 + ca1) * 64 + c0);
    const float4* p10 = (const float4*)(pl + (cb1 * 32 + ca0) * 64 + c0);
    const float4* p11 = (const float4*)(pl + (cb1 * 32 + ca1) * 64 + c0);
#pragma unroll
    for (int q = 0; q < 4; ++q) {
        float4 g00 = p00[q], g01 = p01[q], g10 = p10[q], g11 = p11[q];
        float vx = fmaf(w00, g00.x, fmaf(w01, g01.x, fmaf(w10, g10.x, w11 * g11.x)));
        float vy = fmaf(w00, g00.y, fmaf(w01, g01.y, fmaf(w10, g10.y, w11 * g11.y)));
        float vz = fmaf(w00, g00.z, fmaf(w01, g01.z, fmaf(w10, g10.z, w11 * g11.z)));
        float vw = fmaf(w00, g00.w, fmaf(w01, g01.w, fmaf(w10, g10.w, w11 * g11.w)));
        if (mult) {
            f[4*q+0] *= vx; f[4*q+1] *= vy; f[4*q+2] *= vz; f[4*q+3] *= vw;
        } else {
            f[4*q+0] = vx; f[4*q+1] = vy; f[4*q+2] = vz; f[4*q+3] = vw;
        }
    }
}

// K0: z = MLP(zero features); zero the compaction counter.
__global__ void k_init_z(const float* __restrict__ w2, const float* __restrict__ b1,
                         const float* __restrict__ b2, const float* __restrict__ w3,
                         const float* __restrict__ b3, float* __restrict__ zout,
                         int* __restrict__ cnt) {
    int p = threadIdx.x;  // 128
    if (p == 0) *cnt = 0;
    float h2p = b2[p];
    for (int o = 0; o < 128; ++o) h2p += w2[p * 128 + o] * fmaxf(b1[o], 0.0f);
    __shared__ float red[128];
    red[p] = fmaxf(h2p, 0.0f) * w3[p];
    __syncthreads();
    for (int s = 64; s > 0; s >>= 1) {
        if (p < s) red[p] += red[p + s];
        __syncthreads();
    }
    if (p == 0) *zout = red[0] + b3[0];
}

// K1: planes CHW->HWC (f32) + weights f32->f16 (same [out][in] layout). 864 x 256.
__global__ void k_prep(const float* __restrict__ pxy, const float* __restrict__ pyz,
                       const float* __restrict__ pxz,
                       const float* __restrict__ w1, const float* __restrict__ w2,
                       float* __restrict__ planes, f16* __restrict__ w1h,
                       f16* __restrict__ w2h) {
    int tid = blockIdx.x * 256 + threadIdx.x;
    if (tid < 3 * 65536) {
        int t = tid >> 16;
        int r = tid & 65535;
        int hw = r >> 6;
        int c = r & 63;
        const float* src = (t == 0) ? pxy : ((t == 1) ? pyz : pxz);
        planes[tid] = src[c * 1024 + hw];
    } else if (tid < 3 * 65536 + 8192) {
        int r = tid - 3 * 65536;
        w1h[r] = (f16)w1[r];
    } else if (tid < 3 * 65536 + 8192 + 16384) {
        int r = tid - (3 * 65536 + 8192);
        w2h[r] = (f16)w2[r];
    }
}

// K2: classify; inactive -> out = z; active -> append to list. 4096 x 256.
__global__ void k_classify(const float* __restrict__ coords, const float* __restrict__ zptr,
                           int* __restrict__ cnt, int* __restrict__ list,
                           float* __restrict__ out) {
    int i = blockIdx.x * 256 + threadIdx.x;
    if (i >= MPTS) return;
    float x = coords[3 * i + 0], y = coords[3 * i + 1], z = coords[3 * i + 2];
    float px = fmaf(x, 15.5f, 15.5f);
    float py = fmaf(y, 15.5f, 15.5f);
    float pz = fmaf(z, 15.5f, 15.5f);
    bool act = (px > -1.0f) & (px < 32.0f) & (py > -1.0f) & (py < 32.0f) &
               (pz > -1.0f) & (pz < 32.0f);
    unsigned long long m = __ballot(act);
    int lane = threadIdx.x & 63;
    if (m) {
        int ldr = __ffsll((long long)m) - 1;
        int base = 0;
        if (lane == ldr) base = atomicAdd(cnt, __popcll(m));
        base = __shfl(base, ldr, 64);
        if (act) list[base + __popcll(m & ((1ull << lane) - 1ull))] = i;
    }
    if (!act) out[i] = *zptr;
}

// K3: MFMA MLP over compacted points. 64-pt tiles, 256 thr (4 waves),
// wave w owns output neurons [32w, 32w+32) of both hidden layers; weights in VGPRs.
__global__ __launch_bounds__(256, 2)
void k_mlp(const float* __restrict__ coords, const float* __restrict__ planes,
           const f16* __restrict__ w1h, const f16* __restrict__ w2h,
           const float* __restrict__ b1, const float* __restrict__ b2,
           const float* __restrict__ w3, const float* __restrict__ b3,
           const int* __restrict__ cnt, const int* __restrict__ list,
           float* __restrict__ out) {
    __shared__ __attribute__((aligned(16))) f16 Fs[64 * 64];     // [pt][c], swizzled rows (128 B)
    __shared__ __attribute__((aligned(16))) f16 H1s[64 * 128];   // [pt][o], swizzled rows (256 B)
    __shared__ float outp[4][64];

    const int n = *cnt;
    if (n == 0) return;

    const int t   = threadIdx.x;
    const int wv  = t >> 6;
    const int l   = t & 63;
    const int l15 = l & 15;
    const int lg  = l >> 4;   // 0..3

    const float* pl0 = planes;
    const float* pl1 = planes + 65536;
    const float* pl2 = planes + 131072;

    // ---- per-wave register-resident weight fragments (loaded once) ----
    f16x8 wf1[2][2];   // [ntl][kstep]  layer1 B-frags (w1 rows, k-contig)
    f16x8 wf2[2][4];   // [ntl][kstep]  layer2 B-frags
    float b1v[2], b2v[2], w3v[2];
#pragma unroll
    for (int ntl = 0; ntl < 2; ++ntl) {
        int nrow = (wv * 2 + ntl) * 16 + l15;   // this lane's output-neuron column
#pragma unroll
        for (int ks = 0; ks < 2; ++ks)
            wf1[ntl][ks] = *(const f16x8*)(w1h + nrow * 64 + ks * 32 + lg * 8);
#pragma unroll
        for (int ks = 0; ks < 4; ++ks)
            wf2[ntl][ks] = *(const f16x8*)(w2h + nrow * 128 + ks * 32 + lg * 8);
        b1v[ntl] = b1[nrow];
        b2v[ntl] = b2[nrow];
        w3v[ntl] = w3[nrow];
    }
    const float b3v = b3[0];

    const int ntiles = (n + 63) >> 6;
    for (int tile = blockIdx.x; tile < ntiles; tile += gridDim.x) {
        // ---------- sampling: thread = (pt = t>>2, 16 channels c0 = (t&3)*16) ----------
        {
            int pt = t >> 2, cp = t & 3, c0 = cp * 16;
            int idx = tile * 64 + pt;
            int ic = idx < n ? idx : n - 1;
            int i = list[ic];
            float x = coords[3 * i + 0], y = coords[3 * i + 1], z = coords[3 * i + 2];
            float px = fmaf(x, 15.5f, 15.5f);
            float py = fmaf(y, 15.5f, 15.5f);
            float pz = fmaf(z, 15.5f, 15.5f);
            float feat[16];
            samp16(pl0, px, py, c0, feat, false);
            samp16(pl1, py, pz, c0, feat, true);
            samp16(pl2, px, pz, c0, feat, true);
            int sw = (pt & 7) << 4;
            char* Fb = (char*)Fs + pt * 128;
            f16x8 pk;
#pragma unroll
            for (int j = 0; j < 8; ++j) pk[j] = (f16)feat[j];
            *(f16x8*)(Fb + ((c0 * 2) ^ sw)) = pk;
#pragma unroll
            for (int j = 0; j < 8; ++j) pk[j] = (f16)feat[8 + j];
            *(f16x8*)(Fb + ((c0 * 2 + 16) ^ sw)) = pk;
        }
        __syncthreads();

        // ---------- layer 1: H1[64pt][128] = relu(F x W1^T + b1) ----------
        f32x4 acc[2][4];
#pragma unroll
        for (int ntl = 0; ntl < 2; ++ntl) {
            f32x4 ini = {b1v[ntl], b1v[ntl], b1v[ntl], b1v[ntl]};
#pragma unroll
            for (int Mt = 0; Mt < 4; ++Mt) acc[ntl][Mt] = ini;
        }
#pragma unroll
        for (int Mt = 0; Mt < 4; ++Mt) {
            int row = Mt * 16 + l15;
            const char* rb = (const char*)Fs + row * 128;
            int sw = (row & 7) << 4;
            f16x8 a0 = *(const f16x8*)(rb + ((lg * 16) ^ sw));
            f16x8 a1 = *(const f16x8*)(rb + ((64 + lg * 16) ^ sw));
#pragma unroll
            for (int ntl = 0; ntl < 2; ++ntl) {
                acc[ntl][Mt] = __builtin_amdgcn_mfma_f32_16x16x32_f16(a0, wf1[ntl][0], acc[ntl][Mt], 0, 0, 0);
                acc[ntl][Mt] = __builtin_amdgcn_mfma_f32_16x16x32_f16(a1, wf1[ntl][1], acc[ntl][Mt], 0, 0, 0);
            }
        }
        // relu + store H1 (f16, swizzled)
#pragma unroll
        for (int ntl = 0; ntl < 2; ++ntl) {
            int ncol = (wv * 2 + ntl) * 16 + l15;
#pragma unroll
            for (int Mt = 0; Mt < 4; ++Mt) {
#pragma unroll
                for (int r = 0; r < 4; ++r) {
                    int prow = Mt * 16 + lg * 4 + r;
                    float v = fmaxf(acc[ntl][Mt][r], 0.0f);
                    *(f16*)((char*)H1s + prow * 256 + ((ncol * 2) ^ ((prow & 7) << 4))) = (f16)v;
                }
            }
        }
        __syncthreads();

        // ---------- layer 2: H2[64pt][128] = relu(H1 x W2^T + b2) (acc in regs) ----------
        f32x4 acc2[2][4];
#pragma unroll
        for (int ntl = 0; ntl < 2; ++ntl) {
            f32x4 ini = {b2v[ntl], b2v[ntl], b2v[ntl], b2v[ntl]};
#pragma unroll
            for (int Mt = 0; Mt < 4; ++Mt) acc2[ntl][Mt] = ini;
        }
#pragma unroll
        for (int Mt = 0; Mt < 4; ++Mt) {
            int row = Mt * 16 + l15;
            const char* rb = (const char*)H1s + row * 256;
            int sw = (row & 7) << 4;
            f16x8 a0 = *(const f16x8*)(rb + ((lg * 16) ^ sw));
            f16x8 a1 = *(const f16x8*)(rb + ((64 + lg * 16) ^ sw));
            f16x8 a2 = *(const f16x8*)(rb + ((128 + lg * 16) ^ sw));
            f16x8 a3 = *(const f16x8*)(rb + ((192 + lg * 16) ^ sw));
#pragma unroll
            for (int ntl = 0; ntl < 2; ++ntl) {
                acc2[ntl][Mt] = __builtin_amdgcn_mfma_f32_16x16x32_f16(a0, wf2[ntl][0], acc2[ntl][Mt], 0, 0, 0);
                acc2[ntl][Mt] = __builtin_amdgcn_mfma_f32_16x16x32_f16(a1, wf2[ntl][1], acc2[ntl][Mt], 0, 0, 0);
                acc2[ntl][Mt] = __builtin_amdgcn_mfma_f32_16x16x32_f16(a2, wf2[ntl][2], acc2[ntl][Mt], 0, 0, 0);
                acc2[ntl][Mt] = __builtin_amdgcn_mfma_f32_16x16x32_f16(a3, wf2[ntl][3], acc2[ntl][Mt], 0, 0, 0);
            }
        }

        // ---------- layer 3: out[pt] = sum_n relu(H2) * w3 + b3 ----------
        float part[4][4];
#pragma unroll
        for (int Mt = 0; Mt < 4; ++Mt)
#pragma unroll
            for (int r = 0; r < 4; ++r)
                part[Mt][r] = fmaxf(acc2[0][Mt][r], 0.0f) * w3v[0] +
                              fmaxf(acc2[1][Mt][r], 0.0f) * w3v[1];
#pragma unroll
        for (int off = 1; off <= 8; off <<= 1) {
#pragma unroll
            for (int Mt = 0; Mt < 4; ++Mt)
#pragma unroll
                for (int r = 0; r < 4; ++r)
                    part[Mt][r] += __shfl_xor(part[Mt][r], off, 64);
        }
        if (l15 == 0) {
#pragma unroll
            for (int Mt = 0; Mt < 4; ++Mt)
#pragma unroll
                for (int r = 0; r < 4; ++r)
                    outp[wv][Mt * 16 + lg * 4 + r] = part[Mt][r];
        }
        __syncthreads();
        if (t < 64) {
            int gi = tile * 64 + t;
            if (gi < n) {
                float s = outp[0][t] + outp[1][t] + outp[2][t] + outp[3][t] + b3v;
                out[list[gi]] = s;
            }
        }
        __syncthreads();
    }
}

// Fallback (no workspace): per-thread f32 MLP over all points, original layouts.
__global__ void k_fallback(const float* __restrict__ coords,
                           const float* __restrict__ p0, const float* __restrict__ p1,
                           const float* __restrict__ p2,
                           const float* __restrict__ w1, const float* __restrict__ b1,
                           const float* __restrict__ w2, const float* __restrict__ b2,
                           const float* __restrict__ w3, const float* __restrict__ b3,
                           float* __restrict__ out) {
    int i = blockIdx.x * 256 + threadIdx.x;
    if (i >= MPTS) return;
    float x = coords[3 * i + 0], y = coords[3 * i + 1], z = coords[3 * i + 2];
    float px = fmaf(x, 15.5f, 15.5f);
    float py = fmaf(y, 15.5f, 15.5f);
    float pz = fmaf(z, 15.5f, 15.5f);
    float feat[64];
    // CHW sampling per plane
    const float* pls[3] = {p0, p1, p2};
    float pa[3] = {px, py, px}, pb[3] = {py, pz, pz};
    for (int pidx = 0; pidx < 3; ++pidx) {
        float paf = pa[pidx], pbf = pb[pidx];
        float fa = floorf(paf), fb = floorf(pbf);
        int ia0 = (int)fa, ib0 = (int)fb, ia1 = ia0 + 1, ib1 = ib0 + 1;
        float wa1 = paf - fa, wa0 = 1.0f - wa1, wb1 = pbf - fb, wb0 = 1.0f - wb1;
        float va0 = (ia0 >= 0 && ia0 < 32) ? wa0 : 0.0f;
        float va1 = (ia1 >= 0 && ia1 < 32) ? wa1 : 0.0f;
        float vb0 = (ib0 >= 0 && ib0 < 32) ? wb0 : 0.0f;
        float vb1 = (ib1 >= 0 && ib1 < 32) ? wb1 : 0.0f;
        int ca0 = iclamp(ia0, 0, 31), ca1 = iclamp(ia1, 0, 31);
        int cb0 = iclamp(ib0, 0, 31), cb1 = iclamp(ib1, 0, 31);
        float w00 = va0 * vb0, w01 = va1 * vb0, w10 = va0 * vb1, w11 = va1 * vb1;
        int o00 = cb0 * 32 + ca0, o01 = cb0 * 32 + ca1;
        int o10 = cb1 * 32 + ca0, o11 = cb1 * 32 + ca1;
        const float* pl = pls[pidx];
        for (int c = 0; c < 64; ++c) {
            const float* pc = pl + c * 1024;
            float v = fmaf(w00, pc[o00], fmaf(w01, pc[o01],
                      fmaf(w10, pc[o10], w11 * pc[o11])));
            if (pidx == 0) feat[c] = v; else feat[c] *= v;
        }
    }
    float oa = b3[0];
    for (int half = 0; half < 2; ++half) {
        float h2h[64];
        for (int p = 0; p < 64; ++p) h2h[p] = b2[half * 64 + p];
        for (int o = 0; o < 128; ++o) {
            float a = b1[o];
            for (int c = 0; c < 64; ++c) a = fmaf(feat[c], w1[o * 64 + c], a);
            float r = fmaxf(a, 0.0f);
            for (int p = 0; p < 64; ++p) h2h[p] = fmaf(r, w2[(half * 64 + p) * 128 + o], h2h[p]);
        }
        for (int p = 0; p < 64; ++p) oa = fmaf(fmaxf(h2h[p], 0.0f), w3[half * 64 + p], oa);
    }
    out[i] = oa;
}

extern "C" void kernel_launch(void* const* d_in, const int* in_sizes, int n_in,
                              void* d_out, int out_size, void* d_ws, size_t ws_size,
                              hipStream_t stream) {
    const float* coords = (const float*)d_in[0];
    const float* pxy    = (const float*)d_in[1];
    const float* pyz    = (const float*)d_in[2];
    const float* pxz    = (const float*)d_in[3];
    const float* w1     = (const float*)d_in[4];
    const float* b1     = (const float*)d_in[5];
    const float* w2     = (const float*)d_in[6];
    const float* b2     = (const float*)d_in[7];
    const float* w3     = (const float*)d_in[8];
    const float* b3     = (const float*)d_in[9];
    float* out = (float*)d_out;

    if (ws_size >= WS_NEED) {
        float* zout   = (float*)((char*)d_ws + OFF_Z);
        int*   cnt    = (int*)((char*)d_ws + OFF_CNT);
        float* planes = (float*)((char*)d_ws + OFF_PL);
        f16*   w1h    = (f16*)((char*)d_ws + OFF_W1H);
        f16*   w2h    = (f16*)((char*)d_ws + OFF_W2H);
        int*   list   = (int*)((char*)d_ws + OFF_LIST);

        k_init_z<<<1, 128, 0, stream>>>(w2, b1, b2, w3, b3, zout, cnt);
        k_prep<<<864, 256, 0, stream>>>(pxy, pyz, pxz, w1, w2, planes, w1h, w2h);
        k_classify<<<4096, 256, 0, stream>>>(coords, zout, cnt, list, out);
        k_mlp<<<1024, 256, 0, stream>>>(coords, planes, w1h, w2h,
                                        b1, b2, w3, b3, cnt, list, out);
    } else {
        k_fallback<<<4096, 256, 0, stream>>>(coords, pxy, pyz, pxz,
                                             w1, b1, w2, b2, w3, b3, out);
    }
}

// Round 3
// 129.966 us; speedup vs baseline: 7.0719x; 2.3683x over previous
//
#include <hip/hip_runtime.h>

#define MPTS 1048576

typedef _Float16 f16;
typedef _Float16 f16x8 __attribute__((ext_vector_type(8)));
typedef float f32x4 __attribute__((ext_vector_type(4)));

// ---------------- workspace layout (bytes) ----------------
static const size_t OFF_Z    = 0;                         // float
static const size_t OFF_CNT  = 64;                        // int
static const size_t OFF_PL   = 256;                       // 3 planes HWC f32: 786432 B
static const size_t OFF_W1H  = OFF_PL + 786432;           // 8192 f16
static const size_t OFF_W2H  = OFF_W1H + 16384;           // 16384 f16
static const size_t OFF_BCNT = OFF_W2H + 32768;           // 1024 ints
static const size_t OFF_BOFF = OFF_BCNT + 4096;           // 1024 ints
static const size_t OFF_LIST = OFF_BOFF + 4096;           // M ints
static const size_t WS_NEED  = OFF_LIST + (size_t)MPTS * 4;

__device__ __forceinline__ int iclamp(int v, int lo, int hi) {
    return v < lo ? lo : (v > hi ? hi : v);
}

__device__ __forceinline__ bool isact(float x, float y, float z) {
    float px = fmaf(x, 15.5f, 15.5f);
    float py = fmaf(y, 15.5f, 15.5f);
    float pz = fmaf(z, 15.5f, 15.5f);
    return (px > -1.0f) & (px < 32.0f) & (py > -1.0f) & (py < 32.0f) &
           (pz > -1.0f) & (pz < 32.0f);
}

// -------- bilinear sample of 16 channels (HWC plane [32][32][64] f32) --------
__device__ __forceinline__ void samp16(const float* __restrict__ pl,
                                       float pa, float pb, int c0,
                                       float* __restrict__ f, const bool mult) {
    float fa = floorf(pa), fb = floorf(pb);
    int ia0 = (int)fa, ib0 = (int)fb;
    int ia1 = ia0 + 1, ib1 = ib0 + 1;
    float wa1 = pa - fa, wa0 = 1.0f - wa1;
    float wb1 = pb - fb, wb0 = 1.0f - wb1;
    float va0 = (ia0 >= 0 && ia0 < 32) ? wa0 : 0.0f;
    float va1 = (ia1 >= 0 && ia1 < 32) ? wa1 : 0.0f;
    float vb0 = (ib0 >= 0 && ib0 < 32) ? wb0 : 0.0f;
    float vb1 = (ib1 >= 0 && ib1 < 32) ? wb1 : 0.0f;
    int ca0 = iclamp(ia0, 0, 31), ca1 = iclamp(ia1, 0, 31);
    int cb0 = iclamp(ib0, 0, 31), cb1 = iclamp(ib1, 0, 31);
    float w00 = va0 * vb0, w01 = va1 * vb0, w10 = va0 * vb1, w11 = va1 * vb1;
    const float4* p00 = (const float4*)(pl + (cb0 * 32 + ca0) * 64 + c0);
    const float4* p01 = (const float4*)(pl + (cb0 * 32 + ca1) * 64 + c0);
    const float4* p10 = (const float4*)(pl + (cb1 * 32 + ca0) * 64 + c0);
    const float4* p11 = (const float4*)(pl + (cb1 * 32 + ca1) * 64 + c0);
#pragma unroll
    for (int q = 0; q < 4; ++q) {
        float4 g00 = p00[q], g01 = p01[q], g10 = p10[q], g11 = p11[q];
        float vx = fmaf(w00, g00.x, fmaf(w01, g01.x, fmaf(w10, g10.x, w11 * g11.x)));
        float vy = fmaf(w00, g00.y, fmaf(w01, g01.y, fmaf(w10, g10.y, w11 * g11.y)));
        float vz = fmaf(w00, g00.z, fmaf(w01, g01.z, fmaf(w10, g10.z, w11 * g11.z)));
        float vw = fmaf(w00, g00.w, fmaf(w01, g01.w, fmaf(w10, g10.w, w11 * g11.w)));
        if (mult) {
            f[4*q+0] *= vx; f[4*q+1] *= vy; f[4*q+2] *= vz; f[4*q+3] *= vw;
        } else {
            f[4*q+0] = vx; f[4*q+1] = vy; f[4*q+2] = vz; f[4*q+3] = vw;
        }
    }
}

// K0: z = MLP(zero features).
__global__ void k_init_z(const float* __restrict__ w2, const float* __restrict__ b1,
                         const float* __restrict__ b2, const float* __restrict__ w3,
                         const float* __restrict__ b3, float* __restrict__ zout) {
    int p = threadIdx.x;  // 128
    float h2p = b2[p];
    for (int o = 0; o < 128; ++o) h2p += w2[p * 128 + o] * fmaxf(b1[o], 0.0f);
    __shared__ float red[128];
    red[p] = fmaxf(h2p, 0.0f) * w3[p];
    __syncthreads();
    for (int s = 64; s > 0; s >>= 1) {
        if (p < s) red[p] += red[p + s];
        __syncthreads();
    }
    if (p == 0) *zout = red[0] + b3[0];
}

// K1: planes CHW->HWC (f32) + weights f32->f16. 864 x 256.
__global__ void k_prep(const float* __restrict__ pxy, const float* __restrict__ pyz,
                       const float* __restrict__ pxz,
                       const float* __restrict__ w1, const float* __restrict__ w2,
                       float* __restrict__ planes, f16* __restrict__ w1h,
                       f16* __restrict__ w2h) {
    int tid = blockIdx.x * 256 + threadIdx.x;
    if (tid < 3 * 65536) {
        int t = tid >> 16;
        int r = tid & 65535;
        int hw = r >> 6;
        int c = r & 63;
        const float* src = (t == 0) ? pxy : ((t == 1) ? pyz : pxz);
        planes[tid] = src[c * 1024 + hw];
    } else if (tid < 3 * 65536 + 8192) {
        int r = tid - 3 * 65536;
        w1h[r] = (f16)w1[r];
    } else if (tid < 3 * 65536 + 8192 + 16384) {
        int r = tid - (3 * 65536 + 8192);
        w2h[r] = (f16)w2[r];
    }
}

// K2a: per-block active counts; inactive points get out = z. 1024 x 256, 4 pts/thread.
__global__ void k_count(const float* __restrict__ coords, const float* __restrict__ zptr,
                        int* __restrict__ bcnt, float* __restrict__ out) {
    int t = threadIdx.x, bid = blockIdx.x;
    const float4* c4 = (const float4*)coords + 768 * (size_t)bid + 3 * t;
    float4 a = c4[0], b = c4[1], c = c4[2];
    int base = bid * 1024 + t * 4;
    float z = *zptr;
    bool a0 = isact(a.x, a.y, a.z);
    bool a1 = isact(a.w, b.x, b.y);
    bool a2 = isact(b.z, b.w, c.x);
    bool a3 = isact(c.y, c.z, c.w);
    if (!a0) out[base + 0] = z;
    if (!a1) out[base + 1] = z;
    if (!a2) out[base + 2] = z;
    if (!a3) out[base + 3] = z;
    __shared__ int r[256];
    r[t] = (int)a0 + (int)a1 + (int)a2 + (int)a3;
    __syncthreads();
    for (int s = 128; s > 0; s >>= 1) {
        if (t < s) r[t] += r[t + s];
        __syncthreads();
    }
    if (t == 0) bcnt[bid] = r[0];
}

// K2b: exclusive scan of 1024 block counts; writes total to cnt. 1 x 1024.
__global__ void k_scan(const int* __restrict__ bcnt, int* __restrict__ boff,
                       int* __restrict__ cnt) {
    int t = threadIdx.x;
    __shared__ int s[1024];
    int mine = bcnt[t];
    s[t] = mine;
    __syncthreads();
    for (int off = 1; off < 1024; off <<= 1) {
        int v = (t >= off) ? s[t - off] : 0;
        __syncthreads();
        s[t] += v;
        __syncthreads();
    }
    boff[t] = s[t] - mine;   // exclusive
    if (t == 1023) *cnt = s[1023];
}

// K2c: scatter active indices into list at boff[bid] + local prefix. 1024 x 256.
__global__ void k_scatter(const float* __restrict__ coords, const int* __restrict__ boff,
                          int* __restrict__ list) {
    int t = threadIdx.x, bid = blockIdx.x;
    const float4* c4 = (const float4*)coords + 768 * (size_t)bid + 3 * t;
    float4 a = c4[0], b = c4[1], c = c4[2];
    int base = bid * 1024 + t * 4;
    bool act[4];
    act[0] = isact(a.x, a.y, a.z);
    act[1] = isact(a.w, b.x, b.y);
    act[2] = isact(b.z, b.w, c.x);
    act[3] = isact(c.y, c.z, c.w);
    int mine = (int)act[0] + (int)act[1] + (int)act[2] + (int)act[3];
    __shared__ int s[256];
    s[t] = mine;
    __syncthreads();
    for (int off = 1; off < 256; off <<= 1) {
        int v = (t >= off) ? s[t - off] : 0;
        __syncthreads();
        s[t] += v;
        __syncthreads();
    }
    int pos = boff[bid] + s[t] - mine;
#pragma unroll
    for (int j = 0; j < 4; ++j)
        if (act[j]) list[pos++] = base + j;
}

// K3: MFMA MLP, ONE 64-pt tile per block. Grid = 16384 (worst case), early exit.
__global__ __launch_bounds__(256, 2)
void k_mlp(const float* __restrict__ coords, const float* __restrict__ planes,
           const f16* __restrict__ w1h, const f16* __restrict__ w2h,
           const float* __restrict__ b1, const float* __restrict__ b2,
           const float* __restrict__ w3, const float* __restrict__ b3,
           const int* __restrict__ cnt, const int* __restrict__ list,
           float* __restrict__ out) {
    const int n = *cnt;
    const int tile = blockIdx.x;
    if (tile * 64 >= n) return;

    __shared__ __attribute__((aligned(16))) f16 Fs[64 * 64];     // [pt][c], swizzled 128 B rows
    __shared__ __attribute__((aligned(16))) f16 H1s[64 * 128];   // [pt][o], swizzled 256 B rows
    __shared__ float outp[4][64];

    const int t   = threadIdx.x;
    const int wv  = t >> 6;
    const int l   = t & 63;
    const int l15 = l & 15;
    const int lg  = l >> 4;   // 0..3

    const float* pl0 = planes;
    const float* pl1 = planes + 65536;
    const float* pl2 = planes + 131072;

    // ---- per-wave register-resident weight fragments ----
    f16x8 wf1[2][2];
    f16x8 wf2[2][4];
    float b1v[2], b2v[2], w3v[2];
#pragma unroll
    for (int ntl = 0; ntl < 2; ++ntl) {
        int nrow = (wv * 2 + ntl) * 16 + l15;
#pragma unroll
        for (int ks = 0; ks < 2; ++ks)
            wf1[ntl][ks] = *(const f16x8*)(w1h + nrow * 64 + ks * 32 + lg * 8);
#pragma unroll
        for (int ks = 0; ks < 4; ++ks)
            wf2[ntl][ks] = *(const f16x8*)(w2h + nrow * 128 + ks * 32 + lg * 8);
        b1v[ntl] = b1[nrow];
        b2v[ntl] = b2[nrow];
        w3v[ntl] = w3[nrow];
    }
    const float b3v = b3[0];

    // ---------- sampling: thread = (pt = t>>2, 16 channels c0 = (t&3)*16) ----------
    {
        int pt = t >> 2, c0 = (t & 3) * 16;
        int idx = tile * 64 + pt;
        int ic = idx < n ? idx : n - 1;
        int i = list[ic];
        float x = coords[3 * i + 0], y = coords[3 * i + 1], z = coords[3 * i + 2];
        float px = fmaf(x, 15.5f, 15.5f);
        float py = fmaf(y, 15.5f, 15.5f);
        float pz = fmaf(z, 15.5f, 15.5f);
        float feat[16];
        samp16(pl0, px, py, c0, feat, false);
        samp16(pl1, py, pz, c0, feat, true);
        samp16(pl2, px, pz, c0, feat, true);
        int sw = (pt & 7) << 4;
        char* Fb = (char*)Fs + pt * 128;
        f16x8 pk;
#pragma unroll
        for (int j = 0; j < 8; ++j) pk[j] = (f16)feat[j];
        *(f16x8*)(Fb + ((c0 * 2) ^ sw)) = pk;
#pragma unroll
        for (int j = 0; j < 8; ++j) pk[j] = (f16)feat[8 + j];
        *(f16x8*)(Fb + ((c0 * 2 + 16) ^ sw)) = pk;
    }
    __syncthreads();

    // ---------- layer 1 ----------
    f32x4 acc[2][4];
#pragma unroll
    for (int ntl = 0; ntl < 2; ++ntl) {
        f32x4 ini = {b1v[ntl], b1v[ntl], b1v[ntl], b1v[ntl]};
#pragma unroll
        for (int Mt = 0; Mt < 4; ++Mt) acc[ntl][Mt] = ini;
    }
#pragma unroll
    for (int Mt = 0; Mt < 4; ++Mt) {
        int row = Mt * 16 + l15;
        const char* rb = (const char*)Fs + row * 128;
        int sw = (row & 7) << 4;
        f16x8 a0 = *(const f16x8*)(rb + ((lg * 16) ^ sw));
        f16x8 a1 = *(const f16x8*)(rb + ((64 + lg * 16) ^ sw));
#pragma unroll
        for (int ntl = 0; ntl < 2; ++ntl) {
            acc[ntl][Mt] = __builtin_amdgcn_mfma_f32_16x16x32_f16(a0, wf1[ntl][0], acc[ntl][Mt], 0, 0, 0);
            acc[ntl][Mt] = __builtin_amdgcn_mfma_f32_16x16x32_f16(a1, wf1[ntl][1], acc[ntl][Mt], 0, 0, 0);
        }
    }
#pragma unroll
    for (int ntl = 0; ntl < 2; ++ntl) {
        int ncol = (wv * 2 + ntl) * 16 + l15;
#pragma unroll
        for (int Mt = 0; Mt < 4; ++Mt) {
#pragma unroll
            for (int r = 0; r < 4; ++r) {
                int prow = Mt * 16 + lg * 4 + r;
                float v = fmaxf(acc[ntl][Mt][r], 0.0f);
                *(f16*)((char*)H1s + prow * 256 + ((ncol * 2) ^ ((prow & 7) << 4))) = (f16)v;
            }
        }
    }
    __syncthreads();

    // ---------- layer 2 ----------
    f32x4 acc2[2][4];
#pragma unroll
    for (int ntl = 0; ntl < 2; ++ntl) {
        f32x4 ini = {b2v[ntl], b2v[ntl], b2v[ntl], b2v[ntl]};
#pragma unroll
        for (int Mt = 0; Mt < 4; ++Mt) acc2[ntl][Mt] = ini;
    }
#pragma unroll
    for (int Mt = 0; Mt < 4; ++Mt) {
        int row = Mt * 16 + l15;
        const char* rb = (const char*)H1s + row * 256;
        int sw = (row & 7) << 4;
        f16x8 a0 = *(const f16x8*)(rb + ((lg * 16) ^ sw));
        f16x8 a1 = *(const f16x8*)(rb + ((64 + lg * 16) ^ sw));
        f16x8 a2 = *(const f16x8*)(rb + ((128 + lg * 16) ^ sw));
        f16x8 a3 = *(const f16x8*)(rb + ((192 + lg * 16) ^ sw));
#pragma unroll
        for (int ntl = 0; ntl < 2; ++ntl) {
            acc2[ntl][Mt] = __builtin_amdgcn_mfma_f32_16x16x32_f16(a0, wf2[ntl][0], acc2[ntl][Mt], 0, 0, 0);
            acc2[ntl][Mt] = __builtin_amdgcn_mfma_f32_16x16x32_f16(a1, wf2[ntl][1], acc2[ntl][Mt], 0, 0, 0);
            acc2[ntl][Mt] = __builtin_amdgcn_mfma_f32_16x16x32_f16(a2, wf2[ntl][2], acc2[ntl][Mt], 0, 0, 0);
            acc2[ntl][Mt] = __builtin_amdgcn_mfma_f32_16x16x32_f16(a3, wf2[ntl][3], acc2[ntl][Mt], 0, 0, 0);
        }
    }

    // ---------- layer 3 ----------
    float part[4][4];
#pragma unroll
    for (int Mt = 0; Mt < 4; ++Mt)
#pragma unroll
        for (int r = 0; r < 4; ++r)
            part[Mt][r] = fmaxf(acc2[0][Mt][r], 0.0f) * w3v[0] +
                          fmaxf(acc2[1][Mt][r], 0.0f) * w3v[1];
#pragma unroll
    for (int off = 1; off <= 8; off <<= 1) {
#pragma unroll
        for (int Mt = 0; Mt < 4; ++Mt)
#pragma unroll
            for (int r = 0; r < 4; ++r)
                part[Mt][r] += __shfl_xor(part[Mt][r], off, 64);
    }
    if (l15 == 0) {
#pragma unroll
        for (int Mt = 0; Mt < 4; ++Mt)
#pragma unroll
            for (int r = 0; r < 4; ++r)
                outp[wv][Mt * 16 + lg * 4 + r] = part[Mt][r];
    }
    __syncthreads();
    if (t < 64) {
        int gi = tile * 64 + t;
        if (gi < n) {
            float s = outp[0][t] + outp[1][t] + outp[2][t] + outp[3][t] + b3v;
            out[list[gi]] = s;
        }
    }
}

// Fallback (no workspace): per-thread f32 MLP over all points, original layouts.
__global__ void k_fallback(const float* __restrict__ coords,
                           const float* __restrict__ p0, const float* __restrict__ p1,
                           const float* __restrict__ p2,
                           const float* __restrict__ w1, const float* __restrict__ b1,
                           const float* __restrict__ w2, const float* __restrict__ b2,
                           const float* __restrict__ w3, const float* __restrict__ b3,
                           float* __restrict__ out) {
    int i = blockIdx.x * 256 + threadIdx.x;
    if (i >= MPTS) return;
    float x = coords[3 * i + 0], y = coords[3 * i + 1], z = coords[3 * i + 2];
    float px = fmaf(x, 15.5f, 15.5f);
    float py = fmaf(y, 15.5f, 15.5f);
    float pz = fmaf(z, 15.5f, 15.5f);
    float feat[64];
    const float* pls[3] = {p0, p1, p2};
    float pa[3] = {px, py, px}, pb[3] = {py, pz, pz};
    for (int pidx = 0; pidx < 3; ++pidx) {
        float paf = pa[pidx], pbf = pb[pidx];
        float fa = floorf(paf), fb = floorf(pbf);
        int ia0 = (int)fa, ib0 = (int)fb, ia1 = ia0 + 1, ib1 = ib0 + 1;
        float wa1 = paf - fa, wa0 = 1.0f - wa1, wb1 = pbf - fb, wb0 = 1.0f - wb1;
        float va0 = (ia0 >= 0 && ia0 < 32) ? wa0 : 0.0f;
        float va1 = (ia1 >= 0 && ia1 < 32) ? wa1 : 0.0f;
        float vb0 = (ib0 >= 0 && ib0 < 32) ? wb0 : 0.0f;
        float vb1 = (ib1 >= 0 && ib1 < 32) ? wb1 : 0.0f;
        int ca0 = iclamp(ia0, 0, 31), ca1 = iclamp(ia1, 0, 31);
        int cb0 = iclamp(ib0, 0, 31), cb1 = iclamp(ib1, 0, 31);
        float w00 = va0 * vb0, w01 = va1 * vb0, w10 = va0 * vb1, w11 = va1 * vb1;
        int o00 = cb0 * 32 + ca0, o01 = cb0 * 32 + ca1;
        int o10 = cb1 * 32 + ca0, o11 = cb1 * 32 + ca1;
        const float* pl = pls[pidx];
        for (int c = 0; c < 64; ++c) {
            const float* pc = pl + c * 1024;
            float v = fmaf(w00, pc[o00], fmaf(w01, pc[o01],
                      fmaf(w10, pc[o10], w11 * pc[o11])));
            if (pidx == 0) feat[c] = v; else feat[c] *= v;
        }
    }
    float oa = b3[0];
    for (int half = 0; half < 2; ++half) {
        float h2h[64];
        for (int p = 0; p < 64; ++p) h2h[p] = b2[half * 64 + p];
        for (int o = 0; o < 128; ++o) {
            float a = b1[o];
            for (int c = 0; c < 64; ++c) a = fmaf(feat[c], w1[o * 64 + c], a);
            float r = fmaxf(a, 0.0f);
            for (int p = 0; p < 64; ++p) h2h[p] = fmaf(r, w2[(half * 64 + p) * 128 + o], h2h[p]);
        }
        for (int p = 0; p < 64; ++p) oa = fmaf(fmaxf(h2h[p], 0.0f), w3[half * 64 + p], oa);
    }
    out[i] = oa;
}

extern "C" void kernel_launch(void* const* d_in, const int* in_sizes, int n_in,
                              void* d_out, int out_size, void* d_ws, size_t ws_size,
                              hipStream_t stream) {
    const float* coords = (const float*)d_in[0];
    const float* pxy    = (const float*)d_in[1];
    const float* pyz    = (const float*)d_in[2];
    const float* pxz    = (const float*)d_in[3];
    const float* w1     = (const float*)d_in[4];
    const float* b1     = (const float*)d_in[5];
    const float* w2     = (const float*)d_in[6];
    const float* b2     = (const float*)d_in[7];
    const float* w3     = (const float*)d_in[8];
    const float* b3     = (const float*)d_in[9];
    float* out = (float*)d_out;

    if (ws_size >= WS_NEED) {
        float* zout   = (float*)((char*)d_ws + OFF_Z);
        int*   cnt    = (int*)((char*)d_ws + OFF_CNT);
        float* planes = (float*)((char*)d_ws + OFF_PL);
        f16*   w1h    = (f16*)((char*)d_ws + OFF_W1H);
        f16*   w2h    = (f16*)((char*)d_ws + OFF_W2H);
        int*   bcnt   = (int*)((char*)d_ws + OFF_BCNT);
        int*   boff   = (int*)((char*)d_ws + OFF_BOFF);
        int*   list   = (int*)((char*)d_ws + OFF_LIST);

        k_init_z<<<1, 128, 0, stream>>>(w2, b1, b2, w3, b3, zout);
        k_prep<<<864, 256, 0, stream>>>(pxy, pyz, pxz, w1, w2, planes, w1h, w2h);
        k_count<<<1024, 256, 0, stream>>>(coords, zout, bcnt, out);
        k_scan<<<1, 1024, 0, stream>>>(bcnt, boff, cnt);
        k_scatter<<<1024, 256, 0, stream>>>(coords, boff, list);
        k_mlp<<<16384, 256, 0, stream>>>(coords, planes, w1h, w2h,
                                         b1, b2, w3, b3, cnt, list, out);
    } else {
        k_fallback<<<4096, 256, 0, stream>>>(coords, pxy, pyz, pxz,
                                             w1, b1, w2, b2, w3, b3, out);
    }
}